// Round 1
// baseline (99.202 us; speedup 1.0000x reference)
//
#include <hip/hip_runtime.h>
#include <hip/hip_bf16.h>

// Problem constants (fixed by setup_inputs):
//   T=36, Q=2048, C=42 (num_classes=41), N=128
// Inputs (d_in order):
//   0: pred_logits  float32 [T*Q, C]
//   1: pred_boxes   float32 [T*Q, 4]   (cx,cy,w,h)
//   2: tgt_labels   int32   [N*T]
//   3: tgt_boxes    float32 [N*T, 4]   (cx,cy,w,h)
//   4: tgt_valid    int32   [N*T]
//   5: tgt_original_valid int32 [N*T]
// Output: float32 [Q, N] row-major (q-major), out[q*N+n]

constexpr int T = 36;
constexpr int Q = 2048;
constexpr int C = 42;
constexpr int N = 128;

// ---------------------------------------------------------------------------
// Kernel 1: row softmax of logits, written TRANSPOSED as P2[t][c][q].
// Transposed layout makes kernel 2's class-prob gather fully coalesced:
// a wave (64 consecutive q, same t,n) reads 64 consecutive floats.
// ---------------------------------------------------------------------------
__global__ __launch_bounds__(256) void softmax_transpose_kernel(
    const float* __restrict__ logits, float* __restrict__ P2) {
  constexpr int QB = 64;
  constexpr int LDS_STRIDE = C + 1;  // 43: gcd(43,32)=1 -> conflict-free
  const int t = blockIdx.y;
  const int q0 = blockIdx.x * QB;
  const int tid = threadIdx.x;

  __shared__ float tile[QB * LDS_STRIDE];
  __shared__ float rmax[QB];
  __shared__ float rinv[QB];

  // Coalesced load of 64 rows x 42 cols (contiguous in global).
  const float* src = logits + ((size_t)t * Q + q0) * C;
  for (int i = tid; i < QB * C; i += 256) {
    int r = i / C, c = i % C;
    tile[r * LDS_STRIDE + c] = src[i];
  }
  __syncthreads();

  // Per-row max + sum(exp). 64 threads, one row each.
  if (tid < QB) {
    const float* row = tile + tid * LDS_STRIDE;
    float m = -1e30f;
    for (int c = 0; c < C; ++c) m = fmaxf(m, row[c]);
    float s = 0.f;
    for (int c = 0; c < C; ++c) s += __expf(row[c] - m);
    rmax[tid] = m;
    rinv[tid] = 1.f / s;
  }
  __syncthreads();

  // Coalesced transposed write: consecutive i -> consecutive r -> consecutive q.
  for (int i = tid; i < QB * C; i += 256) {
    int c = i >> 6;       // 0..41
    int r = i & 63;       // 0..63
    float v = __expf(tile[r * LDS_STRIDE + c] - rmax[r]) * rinv[r];
    P2[(size_t)(t * C + c) * Q + q0 + r] = v;
  }
}

// ---------------------------------------------------------------------------
// Kernel 2: per (q,n) cost = sum_t valid*(l1 - prob - iou) / sum_t valid.
// Block: 256 threads = 64 q-lanes x 4 subgroups; each thread owns 4 n's
// (n-tile of 16). Targets staged in LDS (broadcast reads). Epilogue
// transposes through LDS so output stores are float4-coalesced.
// ---------------------------------------------------------------------------
__global__ __launch_bounds__(256) void cost_kernel(
    const float* __restrict__ P2, const float* __restrict__ pred_boxes,
    const int* __restrict__ labels, const float* __restrict__ tboxes,
    const int* __restrict__ valid, const int* __restrict__ ovalid,
    float* __restrict__ out) {
  constexpr int QB = 64;
  constexpr int NB = 16;
  constexpr int RES_STRIDE = NB + 1;  // 17: kills 32-way conflict of stride-16

  const int q0 = blockIdx.x * QB;
  const int n0 = blockIdx.y * NB;
  const int tid = threadIdx.x;
  const int lane = tid & 63;  // q offset
  const int sub = tid >> 6;   // 0..3
  const int q = q0 + lane;

  __shared__ float s_tb[NB * T * 4];
  __shared__ float s_val[NB * T];
  __shared__ int s_id[NB * T];
  __shared__ float s_res[QB * RES_STRIDE];

  // Stage target data for this block's 16 n's.
  for (int i = tid; i < NB * T; i += 256) {
    int n = n0 + i / T;
    int t = i % T;
    int g = n * T + t;
    s_val[i] = (float)valid[g];
    s_id[i] = (ovalid[g] == 0) ? (C - 1) : labels[g];
    float4 tb = ((const float4*)tboxes)[g];
    s_tb[i * 4 + 0] = tb.x;
    s_tb[i * 4 + 1] = tb.y;
    s_tb[i * 4 + 2] = tb.z;
    s_tb[i * 4 + 3] = tb.w;
  }
  __syncthreads();

  float acc[4] = {0.f, 0.f, 0.f, 0.f};
  float vsum[4] = {0.f, 0.f, 0.f, 0.f};

  for (int t = 0; t < T; ++t) {
    // Pred box for (t,q): coalesced float4, reused across 4 n's.
    float4 pb = ((const float4*)pred_boxes)[t * Q + q];
    float px1 = pb.x - 0.5f * pb.z, py1 = pb.y - 0.5f * pb.w;
    float px2 = pb.x + 0.5f * pb.z, py2 = pb.y + 0.5f * pb.w;
    float pa = pb.z * pb.w;
    const float* probs_t = P2 + (size_t)t * C * Q + q;

#pragma unroll
    for (int j = 0; j < 4; ++j) {
      int nl = sub * 4 + j;  // local n 0..15
      int idx = nl * T + t;
      float v = s_val[idx];
      int id = s_id[idx];
      // Coalesced gather: whole wave shares (t,n) -> same id, consecutive q.
      float p = probs_t[(size_t)id * Q];
      float tcx = s_tb[idx * 4 + 0], tcy = s_tb[idx * 4 + 1];
      float tw = s_tb[idx * 4 + 2], th = s_tb[idx * 4 + 3];
      float l1 = 0.25f * (fabsf(pb.x - tcx) + fabsf(pb.y - tcy) +
                          fabsf(pb.z - tw) + fabsf(pb.w - th));
      float tx1 = tcx - 0.5f * tw, ty1 = tcy - 0.5f * th;
      float tx2 = tcx + 0.5f * tw, ty2 = tcy + 0.5f * th;
      float iw = fminf(px2, tx2) - fmaxf(px1, tx1);
      float ih = fminf(py2, ty2) - fmaxf(py1, ty1);
      iw = fmaxf(iw, 0.f);
      ih = fmaxf(ih, 0.f);
      float inter = iw * ih;
      float uni = pa + tw * th - inter;
      float iou = inter / uni;
      acc[j] += v * (l1 - p - iou);
      vsum[j] += v;
    }
  }

  // Transpose results through LDS for coalesced float4 output stores.
#pragma unroll
  for (int j = 0; j < 4; ++j) {
    int nl = sub * 4 + j;
    s_res[lane * RES_STRIDE + nl] = acc[j] / vsum[j];
  }
  __syncthreads();

  int r = tid >> 2;   // 0..63
  int c4 = tid & 3;   // 0..3
  float4 o;
  o.x = s_res[r * RES_STRIDE + c4 * 4 + 0];
  o.y = s_res[r * RES_STRIDE + c4 * 4 + 1];
  o.z = s_res[r * RES_STRIDE + c4 * 4 + 2];
  o.w = s_res[r * RES_STRIDE + c4 * 4 + 3];
  ((float4*)(out + (size_t)(q0 + r) * N + n0))[c4] = o;
}

extern "C" void kernel_launch(void* const* d_in, const int* in_sizes, int n_in,
                              void* d_out, int out_size, void* d_ws, size_t ws_size,
                              hipStream_t stream) {
  const float* logits = (const float*)d_in[0];
  const float* pboxes = (const float*)d_in[1];
  const int* labels = (const int*)d_in[2];
  const float* tboxes = (const float*)d_in[3];
  const int* valid = (const int*)d_in[4];
  const int* ovalid = (const int*)d_in[5];
  float* out = (float*)d_out;

  // Workspace: transposed probs P2[T][C][Q] = 36*42*2048*4 B = 12.4 MB.
  float* P2 = (float*)d_ws;

  dim3 g1(Q / 64, T);
  softmax_transpose_kernel<<<g1, 256, 0, stream>>>(logits, P2);

  dim3 g2(Q / 64, N / 16);
  cost_kernel<<<g2, 256, 0, stream>>>(P2, pboxes, labels, tboxes, valid, ovalid, out);
}

// Round 2
// 88.108 us; speedup vs baseline: 1.1259x; 1.1259x over previous
//
#include <hip/hip_runtime.h>
#include <hip/hip_bf16.h>

// Problem constants (fixed by setup_inputs):
//   T=36, Q=2048, C=42 (num_classes=41), N=128
// Inputs (d_in order):
//   0: pred_logits  float32 [T*Q, C]
//   1: pred_boxes   float32 [T*Q, 4]   (cx,cy,w,h)
//   2: tgt_labels   int32   [N*T]
//   3: tgt_boxes    float32 [N*T, 4]   (cx,cy,w,h)
//   4: tgt_valid    int32   [N*T]
//   5: tgt_original_valid int32 [N*T]
// Output: float32 [Q, N] row-major, out[q*N+n]

constexpr int T = 36;
constexpr int Q = 2048;
constexpr int C = 42;
constexpr int N = 128;

// ---------------------------------------------------------------------------
// Kernel 1: row softmax of logits, written TRANSPOSED as P2[t][c][q].
// Transposed layout makes kernel 2's class-prob gather fully coalesced:
// a wave (64 consecutive q, same (t,n) -> same class id) reads 64
// consecutive floats (256 B line).
// ---------------------------------------------------------------------------
__global__ __launch_bounds__(256) void softmax_transpose_kernel(
    const float* __restrict__ logits, float* __restrict__ P2) {
  constexpr int QB = 64;
  constexpr int LDS_STRIDE = C + 1;  // 43: gcd(43,32)=1 -> conflict-free
  const int t = blockIdx.y;
  const int q0 = blockIdx.x * QB;
  const int tid = threadIdx.x;

  __shared__ float tile[QB * LDS_STRIDE];
  __shared__ float rmax[QB];
  __shared__ float rinv[QB];

  // Coalesced load of 64 rows x 42 cols (contiguous in global).
  const float* src = logits + ((size_t)t * Q + q0) * C;
  for (int i = tid; i < QB * C; i += 256) {
    int r = i / C, c = i % C;
    tile[r * LDS_STRIDE + c] = src[i];
  }
  __syncthreads();

  // Per-row max + sum(exp). 64 threads, one row each.
  if (tid < QB) {
    const float* row = tile + tid * LDS_STRIDE;
    float m = -1e30f;
    for (int c = 0; c < C; ++c) m = fmaxf(m, row[c]);
    float s = 0.f;
    for (int c = 0; c < C; ++c) s += __expf(row[c] - m);
    rmax[tid] = m;
    rinv[tid] = 1.f / s;
  }
  __syncthreads();

  // Coalesced transposed write: lanes 0..63 share c, span 64 consecutive q.
  for (int i = tid; i < QB * C; i += 256) {
    int c = i >> 6;       // 0..41
    int r = i & 63;       // 0..63
    float v = __expf(tile[r * LDS_STRIDE + c] - rmax[r]) * rinv[r];
    P2[(size_t)(t * C + c) * Q + q0 + r] = v;
  }
}

// ---------------------------------------------------------------------------
// Kernel 2: cost[q,n] = sum_t valid*(l1 - prob - iou) / denom[n].
// One (q,n) per thread. Block = 64 q-lanes x 4 n-subgroups; grid (32,32) =
// 1024 blocks = 4 blocks/CU -> 16 waves/CU (was 1 wave/SIMD in R1).
// valid[n][t] is wave-uniform -> branch skips ~50% of iterations with no
// divergence. Targets staged in LDS (broadcast reads, packed id|valid).
// ---------------------------------------------------------------------------
__global__ __launch_bounds__(256) void cost_kernel(
    const float* __restrict__ P2, const float* __restrict__ pred_boxes,
    const int* __restrict__ labels, const float* __restrict__ tboxes,
    const int* __restrict__ valid, const int* __restrict__ ovalid,
    float* __restrict__ out) {
  constexpr int NB = 4;
  constexpr int RES_STRIDE = NB + 1;  // 5: gcd(5,32)=1, conflict-free

  const int q0 = blockIdx.x * 64;
  const int n0 = blockIdx.y * NB;
  const int tid = threadIdx.x;
  const int lane = tid & 63;  // q offset within block
  const int sub = tid >> 6;   // local n 0..3
  const int q = q0 + lane;

  __shared__ float4 s_tb[NB * T];
  __shared__ int s_idv[NB * T];   // (valid<<8) | id
  __shared__ float s_rden[NB];    // 1 / denom
  __shared__ float s_res[64 * RES_STRIDE];

  for (int i = tid; i < NB * T; i += 256) {
    int n = n0 + i / T;
    int t = i % T;
    int g = n * T + t;
    s_idv[i] = ((ovalid[g] == 0) ? (C - 1) : labels[g]) | (valid[g] << 8);
    s_tb[i] = ((const float4*)tboxes)[g];
  }
  if (tid < NB) {
    int n = n0 + tid;
    int s = 0;
    for (int t = 0; t < T; ++t) s += valid[n * T + t];
    s_rden[tid] = 1.f / (float)s;
  }
  __syncthreads();

  float acc = 0.f;
  const float* probs_base = P2 + q;

  for (int t = 0; t < T; ++t) {
    int pk = s_idv[sub * T + t];
    if (pk & 0x100) {  // wave-uniform: whole wave shares (n,t)
      float4 pb = ((const float4*)pred_boxes)[t * Q + q];
      float4 tb = s_tb[sub * T + t];
      int id = pk & 0xff;
      // Coalesced gather: 64 lanes -> 64 consecutive floats.
      float p = probs_base[(size_t)(t * C + id) * Q];

      float l1 = 0.25f * (fabsf(pb.x - tb.x) + fabsf(pb.y - tb.y) +
                          fabsf(pb.z - tb.z) + fabsf(pb.w - tb.w));
      float px1 = pb.x - 0.5f * pb.z, py1 = pb.y - 0.5f * pb.w;
      float px2 = pb.x + 0.5f * pb.z, py2 = pb.y + 0.5f * pb.w;
      float tx1 = tb.x - 0.5f * tb.z, ty1 = tb.y - 0.5f * tb.w;
      float tx2 = tb.x + 0.5f * tb.z, ty2 = tb.y + 0.5f * tb.w;
      float iw = fmaxf(fminf(px2, tx2) - fmaxf(px1, tx1), 0.f);
      float ih = fmaxf(fminf(py2, ty2) - fmaxf(py1, ty1), 0.f);
      float inter = iw * ih;
      float uni = pb.z * pb.w + tb.z * tb.w - inter;
      acc += l1 - p - inter / uni;
    }
  }

  // Transpose through LDS -> 64 float4 row-segment stores.
  s_res[lane * RES_STRIDE + sub] = acc * s_rden[sub];
  __syncthreads();

  if (tid < 64) {
    float4 o;
    o.x = s_res[tid * RES_STRIDE + 0];
    o.y = s_res[tid * RES_STRIDE + 1];
    o.z = s_res[tid * RES_STRIDE + 2];
    o.w = s_res[tid * RES_STRIDE + 3];
    *(float4*)(out + (size_t)(q0 + tid) * N + n0) = o;
  }
}

extern "C" void kernel_launch(void* const* d_in, const int* in_sizes, int n_in,
                              void* d_out, int out_size, void* d_ws, size_t ws_size,
                              hipStream_t stream) {
  const float* logits = (const float*)d_in[0];
  const float* pboxes = (const float*)d_in[1];
  const int* labels = (const int*)d_in[2];
  const float* tboxes = (const float*)d_in[3];
  const int* valid = (const int*)d_in[4];
  const int* ovalid = (const int*)d_in[5];
  float* out = (float*)d_out;

  // Workspace: transposed probs P2[T][C][Q] = 36*42*2048*4 B = 12.4 MB.
  float* P2 = (float*)d_ws;

  dim3 g1(Q / 64, T);
  softmax_transpose_kernel<<<g1, 256, 0, stream>>>(logits, P2);

  dim3 g2(Q / 64, N / 4);
  cost_kernel<<<g2, 256, 0, stream>>>(P2, pboxes, labels, tboxes, valid, ovalid, out);
}